// Round 2
// baseline (11718.821 us; speedup 1.0000x reference)
//
#include <hip/hip_runtime.h>

// LSTM encoder, fully fused persistent kernel.
// 256 WGs (1/CU) = 8 groups x 32 WGs. Group g owns batches [8g, 8g+8).
// WG (grp, mw) owns 64 gate rows {q*512 + mw*16 + j : q in 0..3, j in 0..15};
// W_hh and W_ih slices resident in LDS as bf16 (XOR-swizzled for MFMA reads).
// Per step: group spin-barrier -> stage h(bf16)/x(f32->bf16) -> 26x
// mfma_f32_16x16x32_bf16 per wave (K = 512 hidden + 320 padded input) ->
// C tiles to LDS -> 128 threads do gate nonlinearities + cell update (c in
// registers) -> h written bf16 to global double buffer. Workspace: 128KB+64B.

typedef float  f32x4  __attribute__((ext_vector_type(4)));
typedef __bf16 bf16x8 __attribute__((ext_vector_type(8)));
typedef unsigned short u16x4 __attribute__((ext_vector_type(4)));

#define TSEQ 512
#define INDIM 300
#define HID 512

// LDS byte offsets
#define OWH 0          // W_hh slice: 64 rows x 1024B (512 bf16)
#define OWI 65536      // W_ih slice: 64 rows x 640B (320 bf16, k>=300 zero)
#define OH  106496     // h tile: 16 rows x 1024B (batches 8..15 zero)
#define OX  122880     // x tile: 16 rows x 640B (pads zero)
#define ORED 133120    // C spill: 64*17 f32 = 4352B
#define LDSZ 137472

__device__ __forceinline__ unsigned short f2bf(float f) {
    union { float f; unsigned u; } v; v.f = f;
    unsigned r = v.u + 0x7fffu + ((v.u >> 16) & 1u);  // RNE
    return (unsigned short)(r >> 16);
}

extern "C" __global__ __launch_bounds__(256, 1) void lstm_fused(
    const float* __restrict__ inputs,   // [512][64][300]
    const float* __restrict__ Wih,      // [2048][300]
    const float* __restrict__ Whh,      // [2048][512]
    const float* __restrict__ bih,      // [2048]
    const float* __restrict__ bhh,      // [2048]
    unsigned short* __restrict__ hbuf,  // bf16 [2][64][512]
    unsigned int* __restrict__ cnt,     // [8] group arrival counters
    float* __restrict__ out)            // [64][512]
{
    __shared__ __align__(16) char lds[LDSZ];

    const int tid = threadIdx.x;
    const int wg  = blockIdx.x;
    const int grp = wg & 7;    // same XCD per group under round-robin dispatch
    const int mw  = wg >> 3;   // 0..31: which 16-wide hidden slice

    // ---- zero the pad-bearing LDS regions [OWI, OX+10240) = 67584 B ----
    {
        f32x4 z = {0.0f, 0.0f, 0.0f, 0.0f};
        for (int n = 0; n < 17; ++n) {
            int i = n * 256 + tid;
            if (i < 4224)
                *reinterpret_cast<f32x4*>(lds + OWI + i * 16) = z;
        }
    }
    __syncthreads();

    // ---- stage W_hh slice: 64 rows x 512 f32 -> bf16, XOR-swizzled ----
    for (int n = 0; n < 32; ++n) {
        int i  = n * 256 + tid;   // 0..8191 chunks of 4 floats
        int r  = i >> 7;          // local row 0..63
        int ic = i & 127;
        int q = r >> 4, jj = r & 15;
        const float4 w = *reinterpret_cast<const float4*>(
            Whh + ((size_t)(q * HID + mw * 16 + jj) * HID + ic * 4));
        u16x4 p = {f2bf(w.x), f2bf(w.y), f2bf(w.z), f2bf(w.w)};
        *reinterpret_cast<u16x4*>(lds + OWH + r * 1024 +
                                  ((ic * 8) ^ ((r & 7) << 4))) = p;
    }
    // ---- stage W_ih slice: 64 rows x 300 f32 -> bf16 ----
    for (int n = 0; n < 19; ++n) {
        int i = n * 256 + tid;    // 0..4799
        if (i < 4800) {
            int r  = i / 75;
            int ic = i - r * 75;
            int q = r >> 4, jj = r & 15;
            const float4 w = *reinterpret_cast<const float4*>(
                Wih + ((size_t)(q * HID + mw * 16 + jj) * INDIM + ic * 4));
            u16x4 p = {f2bf(w.x), f2bf(w.y), f2bf(w.z), f2bf(w.w)};
            *reinterpret_cast<u16x4*>(lds + OWI + r * 640 +
                                      ((ic * 8) ^ ((r & 7) << 4))) = p;
        }
    }

    // ---- per-thread roles ----
    const int lane = tid & 63;
    const int wv   = tid >> 6;                  // wave = gate type q
    const int arow = wv * 16 + (lane & 15);     // A local row 0..63
    const int kb16 = (lane >> 4) << 4;          // k-block byte offset in 64B
    const int amask = (arow & 7) << 4;
    const int aoffh = arow * 1024;
    const int aoffi = arow * 640;
    const int bcol  = lane & 15;                // B col = batch (0..7 real)
    const int bmask = (bcol & 7) << 4;
    const int boffh = bcol * 1024;
    const int boffi = bcol * 640;

    // assembly roles (tid < 128): hidden j = aj, batch b = ab
    const int aj = tid & 15;
    const int ab = tid >> 4;
    float bias0 = 0.f, bias1 = 0.f, bias2 = 0.f, bias3 = 0.f;
    if (tid < 128) {
        int hidx = mw * 16 + aj;
        bias0 = bih[0 * HID + hidx] + bhh[0 * HID + hidx];
        bias1 = bih[1 * HID + hidx] + bhh[1 * HID + hidx];
        bias2 = bih[2 * HID + hidx] + bhh[2 * HID + hidx];
        bias3 = bih[3 * HID + hidx] + bhh[3 * HID + hidx];
    }
    float cst = 0.0f;  // cell state, persists in registers

    float* red = reinterpret_cast<float*>(lds + ORED);

    __syncthreads();   // W staged

#pragma unroll 1
    for (int t = 0; t < TSEQ; ++t) {
        // ---- group barrier: all 32 WGs finished step t-1 ----
        if (t > 0) {
            if (tid == 0) {
                const unsigned target = (unsigned)t * 32u;
                while (__hip_atomic_load(cnt + grp, __ATOMIC_RELAXED,
                                         __HIP_MEMORY_SCOPE_AGENT) < target)
                    __builtin_amdgcn_s_sleep(2);
            }
            __syncthreads();
            __builtin_amdgcn_fence(__ATOMIC_ACQUIRE, "agent");
        }

        // ---- stage h_t: 8 x 512 bf16 (512 x 16B chunks) ----
        {
            const unsigned short* hsrc =
                hbuf + (size_t)(t & 1) * 64 * HID + (size_t)grp * 8 * HID;
#pragma unroll
            for (int n = 0; n < 2; ++n) {
                int i = n * 256 + tid;    // 0..511
                int b = i >> 6;
                int c = i & 63;
                const float4 v = *reinterpret_cast<const float4*>(
                    hsrc + (size_t)b * HID + c * 8);
                *reinterpret_cast<float4*>(lds + OH + b * 1024 +
                                           ((c * 16) ^ ((b & 7) << 4))) = v;
            }
        }
        // ---- stage x_t: 8 x 300 f32 -> bf16 (600 float4 chunks) ----
#pragma unroll
        for (int n = 0; n < 3; ++n) {
            int i = n * 256 + tid;
            if (i < 600) {
                int b  = i / 75;
                int ic = i - b * 75;
                const float4 v = *reinterpret_cast<const float4*>(
                    inputs + ((size_t)t * 64 + grp * 8 + b) * INDIM + ic * 4);
                u16x4 p = {f2bf(v.x), f2bf(v.y), f2bf(v.z), f2bf(v.w)};
                *reinterpret_cast<u16x4*>(lds + OX + b * 640 +
                                          ((ic * 8) ^ ((b & 7) << 4))) = p;
            }
        }
        __syncthreads();

        // ---- MFMA: gates[64][16] = Wh(64x512) h^T + Wi(64x320) x^T ----
        f32x4 acc0 = {0.f, 0.f, 0.f, 0.f};
        f32x4 acc1 = {0.f, 0.f, 0.f, 0.f};
#pragma unroll
        for (int m = 0; m < 16; ++m) {
            bf16x8 a = *reinterpret_cast<const bf16x8*>(
                lds + OWH + aoffh + ((m * 64 + kb16) ^ amask));
            bf16x8 b = *reinterpret_cast<const bf16x8*>(
                lds + OH + boffh + ((m * 64 + kb16) ^ bmask));
            if (m & 1) acc1 = __builtin_amdgcn_mfma_f32_16x16x32_bf16(a, b, acc1, 0, 0, 0);
            else       acc0 = __builtin_amdgcn_mfma_f32_16x16x32_bf16(a, b, acc0, 0, 0, 0);
        }
#pragma unroll
        for (int m = 0; m < 10; ++m) {
            bf16x8 a = *reinterpret_cast<const bf16x8*>(
                lds + OWI + aoffi + ((m * 64 + kb16) ^ amask));
            bf16x8 b = *reinterpret_cast<const bf16x8*>(
                lds + OX + boffi + ((m * 64 + kb16) ^ bmask));
            if (m & 1) acc1 = __builtin_amdgcn_mfma_f32_16x16x32_bf16(a, b, acc1, 0, 0, 0);
            else       acc0 = __builtin_amdgcn_mfma_f32_16x16x32_bf16(a, b, acc0, 0, 0, 0);
        }
        f32x4 accv = acc0 + acc1;

        // C layout (m89): col = lane&15, row = (lane>>4)*4 + reg
        {
            int rbase = (wv * 16 + ((lane >> 4) << 2)) * 17 + bcol;
            red[rbase + 0]  = accv.x;
            red[rbase + 17] = accv.y;
            red[rbase + 34] = accv.z;
            red[rbase + 51] = accv.w;
        }
        __syncthreads();

        // ---- gate nonlinearities + cell update ----
        if (tid < 128) {
            float gi = bias0 + red[(0 * 16 + aj) * 17 + ab];
            float gf = bias1 + red[(1 * 16 + aj) * 17 + ab];
            float gg = bias2 + red[(2 * 16 + aj) * 17 + ab];
            float go = bias3 + red[(3 * 16 + aj) * 17 + ab];
            float ig = 1.0f / (1.0f + __expf(-gi));
            float fg = 1.0f / (1.0f + __expf(-gf));
            float cg = tanhf(gg);
            float og = 1.0f / (1.0f + __expf(-go));
            cst = fg * cst + ig * cg;
            float hv = og * tanhf(cst);
            if (t == TSEQ - 1) {
                out[(size_t)(grp * 8 + ab) * HID + mw * 16 + aj] = hv;
            } else {
                hbuf[(size_t)((t + 1) & 1) * 64 * HID +
                     (size_t)(grp * 8 + ab) * HID + mw * 16 + aj] = f2bf(hv);
                __threadfence();  // device-scope release of the h store
            }
        }
        __syncthreads();

        if (t < TSEQ - 1 && tid == 0) {
            __hip_atomic_fetch_add(cnt + grp, 1u, __ATOMIC_RELEASE,
                                   __HIP_MEMORY_SCOPE_AGENT);
        }
    }
}

extern "C" void kernel_launch(void* const* d_in, const int* in_sizes, int n_in,
                              void* d_out, int out_size, void* d_ws, size_t ws_size,
                              hipStream_t stream) {
    const float* inputs = (const float*)d_in[0];
    const float* Wih    = (const float*)d_in[1];
    const float* Whh    = (const float*)d_in[2];
    const float* bih    = (const float*)d_in[3];
    const float* bhh    = (const float*)d_in[4];
    float* out = (float*)d_out;

    // workspace: hbuf bf16 [2][64][512] = 131072 B, then 8 counters
    unsigned short* hbuf = (unsigned short*)d_ws;
    unsigned int*   cnt  = (unsigned int*)((char*)d_ws + 131072);

    hipMemsetAsync(d_ws, 0, 131072 + 64, stream);

    void* args[] = {(void*)&inputs, (void*)&Wih, (void*)&Whh, (void*)&bih,
                    (void*)&bhh,    (void*)&hbuf, (void*)&cnt, (void*)&out};
    hipLaunchCooperativeKernel(reinterpret_cast<void*>(lstm_fused),
                               dim3(256), dim3(256), args, 0, stream);
}

// Round 3
// 1263.057 us; speedup vs baseline: 9.2781x; 9.2781x over previous
//
#include <hip/hip_runtime.h>

// LSTM encoder, fully fused persistent kernel, fence-free dataflow sync.
// 256 WGs (1/CU) = 8 groups x 32 WGs. Group g owns batches [8g, 8g+8).
// WG (grp, mw) owns 64 gate rows {q*512 + mw*16 + j}; W_hh/W_ih slices live
// in LDS as bf16 (XOR-swizzled). h is exchanged through global memory as
// 32-bit words (tag<<16)|bf16, written/read with RELAXED agent-scope atomics
// (sc1 accesses, coherent at the Infinity Cache) — no fences, no RMW, no
// barrier counters. Consumers poll the tags embedded in the data.

typedef float  f32x4  __attribute__((ext_vector_type(4)));
typedef __bf16 bf16x8 __attribute__((ext_vector_type(8)));
typedef unsigned short u16x4 __attribute__((ext_vector_type(4)));

#define TSEQ 512
#define INDIM 300
#define HID 512

// LDS byte offsets
#define OWH 0          // W_hh slice: 64 rows x 1024B (512 bf16)
#define OWI 65536      // W_ih slice: 64 rows x 640B (320 bf16, k>=300 zero)
#define OH  106496     // h tile: 16 rows x 1024B (batches 8..15 stay zero)
#define OX  122880     // x tile: 16 rows x 640B (pads stay zero)
#define ORED 133120    // C spill: 64*17 f32 = 4352B
#define LDSZ 137472

__device__ __forceinline__ unsigned short f2bf(float f) {
    union { float f; unsigned u; } v; v.f = f;
    unsigned r = v.u + 0x7fffu + ((v.u >> 16) & 1u);  // RNE
    return (unsigned short)(r >> 16);
}
__device__ __forceinline__ float fsigmoid(float x) {
    return 1.0f / (1.0f + __expf(-x));
}
__device__ __forceinline__ float ftanh(float x) {
    float e = __expf(2.0f * x);           // inf-safe: +inf -> 1, 0 -> -1
    return 1.0f - 2.0f / (e + 1.0f);
}

extern "C" __global__ __launch_bounds__(256, 1) void lstm_fused(
    const float* __restrict__ inputs,   // [512][64][300]
    const float* __restrict__ Wih,      // [2048][300]
    const float* __restrict__ Whh,      // [2048][512]
    const float* __restrict__ bih,      // [2048]
    const float* __restrict__ bhh,      // [2048]
    unsigned int* __restrict__ hcomm,   // [2][64][512] (tag<<16)|bf16
    float* __restrict__ out)            // [64][512]
{
    __shared__ __align__(16) char lds[LDSZ];

    const int tid = threadIdx.x;
    const int wg  = blockIdx.x;
    const int grp = wg & 7;
    const int mw  = wg >> 3;

    // ---- zero pad-bearing LDS [OWI, OX+10240) = 67584 B ----
    {
        f32x4 z = {0.0f, 0.0f, 0.0f, 0.0f};
        for (int n = 0; n < 17; ++n) {
            int i = n * 256 + tid;
            if (i < 4224)
                *reinterpret_cast<f32x4*>(lds + OWI + i * 16) = z;
        }
    }
    __syncthreads();

    // ---- stage W_hh slice (bf16, XOR-swizzled) ----
    for (int n = 0; n < 32; ++n) {
        int i  = n * 256 + tid;
        int r  = i >> 7;
        int ic = i & 127;
        int q = r >> 4, jj = r & 15;
        const float4 w = *reinterpret_cast<const float4*>(
            Whh + ((size_t)(q * HID + mw * 16 + jj) * HID + ic * 4));
        u16x4 p = {f2bf(w.x), f2bf(w.y), f2bf(w.z), f2bf(w.w)};
        *reinterpret_cast<u16x4*>(lds + OWH + r * 1024 +
                                  ((ic * 8) ^ ((r & 7) << 4))) = p;
    }
    // ---- stage W_ih slice ----
    for (int n = 0; n < 19; ++n) {
        int i = n * 256 + tid;
        if (i < 4800) {
            int r  = i / 75;
            int ic = i - r * 75;
            int q = r >> 4, jj = r & 15;
            const float4 w = *reinterpret_cast<const float4*>(
                Wih + ((size_t)(q * HID + mw * 16 + jj) * INDIM + ic * 4));
            u16x4 p = {f2bf(w.x), f2bf(w.y), f2bf(w.z), f2bf(w.w)};
            *reinterpret_cast<u16x4*>(lds + OWI + r * 640 +
                                      ((ic * 8) ^ ((r & 7) << 4))) = p;
        }
    }

    // ---- per-thread MFMA roles ----
    const int lane = tid & 63;
    const int wv   = tid >> 6;
    const int arow = wv * 16 + (lane & 15);
    const int kb16 = (lane >> 4) << 4;
    const int amask = (arow & 7) << 4;
    const int aoffh = arow * 1024;
    const int aoffi = arow * 640;
    const int bcol  = lane & 15;
    const int bmask = (bcol & 7) << 4;
    const int boffh = bcol * 1024;
    const int boffi = bcol * 640;

    // assembly roles (tid < 128)
    const int aj = tid & 15;
    const int ab = tid >> 4;
    float bias0 = 0.f, bias1 = 0.f, bias2 = 0.f, bias3 = 0.f;
    if (tid < 128) {
        int hidx = mw * 16 + aj;
        bias0 = bih[0 * HID + hidx] + bhh[0 * HID + hidx];
        bias1 = bih[1 * HID + hidx] + bhh[1 * HID + hidx];
        bias2 = bih[2 * HID + hidx] + bhh[2 * HID + hidx];
        bias3 = bih[3 * HID + hidx] + bhh[3 * HID + hidx];
    }
    float cst = 0.0f;

    float* red = reinterpret_cast<float*>(lds + ORED);

    __syncthreads();   // weights staged

#pragma unroll 1
    for (int t = 0; t < TSEQ; ++t) {
        // ---- stage x_t: 8 x 300 f32 -> bf16 ----
#pragma unroll
        for (int n = 0; n < 3; ++n) {
            int i = n * 256 + tid;
            if (i < 600) {
                int b  = i / 75;
                int ic = i - b * 75;
                const float4 v = *reinterpret_cast<const float4*>(
                    inputs + ((size_t)t * 64 + grp * 8 + b) * INDIM + ic * 4);
                u16x4 p = {f2bf(v.x), f2bf(v.y), f2bf(v.z), f2bf(v.w)};
                *reinterpret_cast<u16x4*>(lds + OX + b * 640 +
                                          ((ic * 8) ^ ((b & 7) << 4))) = p;
            }
        }
        __syncthreads();   // SYNC1: x staged

        // ---- issue h poll loads (overlap with x MFMAs) ----
        unsigned long long hv64[8];
        const unsigned long long* hc = reinterpret_cast<const unsigned long long*>(
            hcomm + (size_t)(t & 1) * 32768) + (size_t)grp * 2048 + tid;
        if (t > 0) {
#pragma unroll
            for (int b = 0; b < 8; ++b)
                hv64[b] = __hip_atomic_load(hc + b * 256, __ATOMIC_RELAXED,
                                            __HIP_MEMORY_SCOPE_AGENT);
        }

        // ---- x-part MFMAs ----
        f32x4 acc0 = {0.f, 0.f, 0.f, 0.f};
        f32x4 acc1 = {0.f, 0.f, 0.f, 0.f};
#pragma unroll
        for (int m = 0; m < 10; ++m) {
            bf16x8 a = *reinterpret_cast<const bf16x8*>(
                lds + OWI + aoffi + ((m * 64 + kb16) ^ amask));
            bf16x8 b = *reinterpret_cast<const bf16x8*>(
                lds + OX + boffi + ((m * 64 + kb16) ^ bmask));
            if (m & 1) acc1 = __builtin_amdgcn_mfma_f32_16x16x32_bf16(a, b, acc1, 0, 0, 0);
            else       acc0 = __builtin_amdgcn_mfma_f32_16x16x32_bf16(a, b, acc0, 0, 0, 0);
        }

        // ---- check tags, retry stragglers, stage h into LDS ----
        if (t > 0) {
            const unsigned long long expect =
                ((unsigned long long)t << 48) | ((unsigned long long)t << 16);
            const unsigned long long tmask = 0xffff0000ffff0000ull;
#pragma unroll
            for (int b = 0; b < 8; ++b) {
                while ((hv64[b] & tmask) != expect) {
                    __builtin_amdgcn_s_sleep(1);
                    hv64[b] = __hip_atomic_load(hc + b * 256, __ATOMIC_RELAXED,
                                                __HIP_MEMORY_SCOPE_AGENT);
                }
                unsigned pk = (unsigned)(hv64[b] & 0xffffu) |
                              ((unsigned)((hv64[b] >> 32) & 0xffffu) << 16);
                *reinterpret_cast<unsigned*>(
                    lds + OH + b * 1024 + ((tid * 4) ^ ((b & 7) << 4))) = pk;
            }
        }
        __syncthreads();   // SYNC2: h staged

        // ---- h-part MFMAs ----
        if (t > 0) {
#pragma unroll
            for (int m = 0; m < 16; ++m) {
                bf16x8 a = *reinterpret_cast<const bf16x8*>(
                    lds + OWH + aoffh + ((m * 64 + kb16) ^ amask));
                bf16x8 b = *reinterpret_cast<const bf16x8*>(
                    lds + OH + boffh + ((m * 64 + kb16) ^ bmask));
                if (m & 1) acc1 = __builtin_amdgcn_mfma_f32_16x16x32_bf16(a, b, acc1, 0, 0, 0);
                else       acc0 = __builtin_amdgcn_mfma_f32_16x16x32_bf16(a, b, acc0, 0, 0, 0);
            }
        }
        f32x4 accv = acc0 + acc1;

        // ---- spill C (m89 layout: col=lane&15, row=(lane>>4)*4+reg) ----
        {
            int rbase = (wv * 16 + ((lane >> 4) << 2)) * 17 + bcol;
            red[rbase + 0]  = accv.x;
            red[rbase + 17] = accv.y;
            red[rbase + 34] = accv.z;
            red[rbase + 51] = accv.w;
        }
        __syncthreads();   // SYNC3: C spilled

        // ---- gates + cell update + publish h ----
        if (tid < 128) {
            float gi = bias0 + red[(0 * 16 + aj) * 17 + ab];
            float gf = bias1 + red[(1 * 16 + aj) * 17 + ab];
            float gg = bias2 + red[(2 * 16 + aj) * 17 + ab];
            float go = bias3 + red[(3 * 16 + aj) * 17 + ab];
            float ig = fsigmoid(gi);
            float fg = fsigmoid(gf);
            float cg = ftanh(gg);
            float og = fsigmoid(go);
            cst = fg * cst + ig * cg;
            float hv = og * ftanh(cst);
            if (t == TSEQ - 1) {
                out[(size_t)(grp * 8 + ab) * HID + mw * 16 + aj] = hv;
            } else {
                unsigned word = ((unsigned)(t + 1) << 16) | (unsigned)f2bf(hv);
                __hip_atomic_store(
                    hcomm + (size_t)((t + 1) & 1) * 32768 +
                        (size_t)(grp * 8 + ab) * 512 + mw * 16 + aj,
                    word, __ATOMIC_RELAXED, __HIP_MEMORY_SCOPE_AGENT);
            }
        }
        __syncthreads();   // SYNC4: red consumed before next iter overwrites
    }
}

extern "C" void kernel_launch(void* const* d_in, const int* in_sizes, int n_in,
                              void* d_out, int out_size, void* d_ws, size_t ws_size,
                              hipStream_t stream) {
    const float* inputs = (const float*)d_in[0];
    const float* Wih    = (const float*)d_in[1];
    const float* Whh    = (const float*)d_in[2];
    const float* bih    = (const float*)d_in[3];
    const float* bhh    = (const float*)d_in[4];
    float* out = (float*)d_out;

    unsigned int* hcomm = (unsigned int*)d_ws;   // [2][64][512] u32 = 256 KB

    // clear tags each call (prevents stale-tag matches across graph replays)
    hipMemsetAsync(hcomm, 0, 2 * 64 * 512 * sizeof(unsigned int), stream);

    void* args[] = {(void*)&inputs, (void*)&Wih, (void*)&Whh, (void*)&bih,
                    (void*)&bhh,    (void*)&hcomm, (void*)&out};
    hipLaunchCooperativeKernel(reinterpret_cast<void*>(lstm_fused),
                               dim3(256), dim3(256), args, 0, stream);
}